// Round 7
// baseline (275.057 us; speedup 1.0000x reference)
//
#include <hip/hip_runtime.h>

constexpr int N_VARS   = 2048;
constexpr int NODES    = 4096;
constexpr int N_LAYERS = 8;
constexpr int BATCH    = 8192;
constexpr int THREADS  = 512;               // 8 waves/block, 2 blocks/CU (80 KB LDS)
constexpr int RPB      = 2;                 // batch rows per block
constexpr int NPT      = NODES / THREADS;   // 8 nodes/thread/layer
// A duplicated: A0[4096] + A1[4096] float2 (64 KB) + B[4096] u32 (16 KB)
constexpr size_t SMEM  = (size_t)NODES * 2 * 8 + (size_t)NODES * 4;  // 81920 B

// ---- bf16x2 word = row0 bf16 (low 16) | row1 bf16 (high 16) ----
__device__ __forceinline__ float bflo(unsigned w) { return __uint_as_float(w << 16); }
__device__ __forceinline__ float bfhi(unsigned w) { return __uint_as_float(w & 0xffff0000u); }
__device__ __forceinline__ unsigned bfpack(float a, float b) {   // RNE both
  unsigned ua = __float_as_uint(a), ub = __float_as_uint(b);
  ua = (ua + 0x7fffu + ((ua >> 16) & 1u)) >> 16;
  ub = (ub + 0x7fffu + ((ub >> 16) & 1u)) & 0xffff0000u;
  return ua | ub;
}

// MODE: 0 = pre-packed/balanced ushort4 (d_ws; even layers carry materialized
//        13-bit dual-copy addresses), 1 = raw int32, 2 = raw int64 words
template <int MODE>
__device__ __forceinline__ ushort4 get_idx(const void* p, int n) {
  if (MODE == 0) return ((const ushort4*)p)[n];
  if (MODE == 1) {
    int4 c = ((const int4*)p)[n];
    return make_ushort4((unsigned short)c.x, (unsigned short)c.y,
                        (unsigned short)c.z, (unsigned short)c.w);
  }
  const int* q = (const int*)p + (size_t)n * 8;
  return make_ushort4((unsigned short)q[0], (unsigned short)q[2],
                      (unsigned short)q[4], (unsigned short)q[6]);
}
template <int MODE> __device__ __forceinline__ size_t layer_bytes() {
  return MODE == 0 ? (size_t)NODES * 8 : MODE == 1 ? (size_t)NODES * 16
                                                   : (size_t)NODES * 32;
}

// Prod layer: gather fp32 float2 from A (dual-copy, index pre-materialized,
// 0..8191), multiply fp32, store bf16x2 to B.
template <int MODE>
__device__ __forceinline__ void prod_pass(const float2* A, unsigned* B,
                                          const void* idx, int t) {
#pragma unroll
  for (int i = 0; i < NPT; ++i) {
    const int n = t + i * THREADS;
    ushort4 c = get_idx<MODE>(idx, n);
    float2 a = A[c.x], b = A[c.y], d = A[c.z], e = A[c.w];
    B[n] = bfpack(a.x * b.x * d.x * e.x, a.y * b.y * d.y * e.y);
  }
}

// Sum layer: gather bf16x2 from B, add fp32, store fp32 float2 to BOTH A copies.
template <int MODE>
__device__ __forceinline__ void sum_pass(const unsigned* B, float2* A,
                                         const void* idx, int t) {
#pragma unroll
  for (int i = 0; i < NPT; ++i) {
    const int n = t + i * THREADS;
    ushort4 c = get_idx<MODE>(idx, n);
    unsigned a = B[c.x], b = B[c.y], d = B[c.z], e = B[c.w];
    float2 v = make_float2(bflo(a) + bflo(b) + bflo(d) + bflo(e),
                           bfhi(a) + bfhi(b) + bfhi(d) + bfhi(e));
    A[n]                 = v;           // copy 0: pair n&15
    A[NODES + (n ^ 8)]   = v;           // copy 1: pair (n&15)^8, conflict-free
  }
}

template <int MODE>
__device__ __forceinline__ void spn_body(const float* __restrict__ x,
                                         const unsigned char* __restrict__ marg,
                                         const void* __restrict__ idx,
                                         float* __restrict__ out,
                                         float2* A,          // 2*4096 fp32x2 = 64 KB
                                         unsigned* B) {      // 4096 bf16x2  = 16 KB
  const int t = threadIdx.x;
  const int row0 = blockIdx.x * RPB;
  const float* x0 = x + (size_t)row0 * N_VARS;
  const float* x1 = x0 + N_VARS;

#pragma unroll
  for (int i = 0; i < N_VARS / THREADS; ++i) {  // 4 iterations
    const int j = t + i * THREADS;
    const float a = x0[j], b = x1[j];
    const bool m = marg[j] != 0;
    float2 lo = make_float2(m ? 1.f : a,       m ? 1.f : b);
    float2 hi = make_float2(m ? 1.f : 1.f - a, m ? 1.f : 1.f - b);
    A[j]                          = lo;
    A[NODES + (j ^ 8)]            = lo;
    A[N_VARS + j]                 = hi;
    A[NODES + ((N_VARS + j) ^ 8)] = hi;
  }

  const char* ib = (const char*)idx;
  const size_t LB = layer_bytes<MODE>();
  __syncthreads();
  prod_pass<MODE>(A, B, ib + 0 * LB, t); __syncthreads();   // L0
  sum_pass <MODE>(B, A, ib + 1 * LB, t); __syncthreads();   // L1
  prod_pass<MODE>(A, B, ib + 2 * LB, t); __syncthreads();   // L2
  sum_pass <MODE>(B, A, ib + 3 * LB, t); __syncthreads();   // L3
  prod_pass<MODE>(A, B, ib + 4 * LB, t); __syncthreads();   // L4
  sum_pass <MODE>(B, A, ib + 5 * LB, t); __syncthreads();   // L5
  prod_pass<MODE>(A, B, ib + 6 * LB, t); __syncthreads();   // L6

  // L7 (sum) fused into node reduction.
  float s0 = 0.f, s1 = 0.f;
  {
    const void* L7 = ib + 7 * LB;
#pragma unroll
    for (int i = 0; i < NPT; ++i) {
      const int n = t + i * THREADS;
      ushort4 c = get_idx<MODE>(L7, n);
      unsigned a = B[c.x], b = B[c.y], d = B[c.z], e = B[c.w];
      s0 += bflo(a) + bflo(b) + bflo(d) + bflo(e);
      s1 += bfhi(a) + bfhi(b) + bfhi(d) + bfhi(e);
    }
  }
#pragma unroll
  for (int off = 32; off > 0; off >>= 1) {
    s0 += __shfl_down(s0, off);
    s1 += __shfl_down(s1, off);
  }
  if ((t & 63) == 0) A[t >> 6] = make_float2(s0, s1);  // 8 wave partials
  __syncthreads();
  if (t == 0) {
    float2 tot = A[0];
#pragma unroll
    for (int w = 1; w < THREADS / 64; ++w) { tot.x += A[w].x; tot.y += A[w].y; }
    ((float2*)out)[blockIdx.x] = tot;
  }
}

extern __shared__ char smem[];

__global__ __launch_bounds__(THREADS) void spn_packed(
    const float* __restrict__ x, const unsigned char* __restrict__ marg,
    const ushort4* __restrict__ idx, float* __restrict__ out) {
  float2*   A = (float2*)smem;                  // 64 KB (two copies)
  unsigned* B = (unsigned*)(smem + NODES * 16); // 16 KB
  spn_body<0>(x, marg, idx, out, A, B);
}

__global__ __launch_bounds__(THREADS) void spn_raw(
    const float* __restrict__ x, const unsigned char* __restrict__ marg,
    const int* __restrict__ cidx, float* __restrict__ out) {
  float2*   A = (float2*)smem;   // raw indices < 4096 -> read copy 0 only (ok)
  unsigned* B = (unsigned*)(smem + NODES * 16);
  int acc = 0;  // int64 storage => odd words all zero (indices < 4096)
#pragma unroll
  for (int k = 0; k < 8; ++k) acc |= cidx[2 * k + 1];
  if (acc == 0) spn_body<2>(x, marg, cidx, out, A, B);
  else          spn_body<1>(x, marg, cidx, out, A, B);
}

// Fused pack + bank-balance, one WAVE per 64-node instruction-group.
// Prod/sum commute -> permute each node's 4 children across the 4 gather
// slots. Even (prod) layers additionally choose one of TWO A-copies per
// child (power-of-two-choices): physical bank-pair = (c&15) ^ (8*copy);
// the winning copy is materialized into the stored index:
//     out = (copy<<12) | (c ^ (copy<<3))   -> direct float2 index 0..8191.
// Odd (sum) layers: single copy, bank = c & 31, plain index.
// Histogram distributed in registers: lane b holds bank b's four 8-bit
// slot counts packed in a u32; decisions computed redundantly in all lanes
// from __shfl'd data (pure function -> identical results).
__global__ __launch_bounds__(64) void prep_idx(const int* __restrict__ cidx,
                                               ushort4* __restrict__ out) {
  const int gid  = blockIdx.x;        // 0..511
  const int l    = gid >> 6;          // layer
  const int cgrp = gid & 63;          // 64-node chunk within layer
  const int lane = threadIdx.x;       // 0..63
  const size_t n = (size_t)l * NODES + cgrp * 64 + lane;

  int acc = 0;                        // i64 storage detect (uniform)
#pragma unroll
  for (int k = 0; k < 8; ++k) acc |= cidx[2 * k + 1];

  ushort4 r;
  if (acc == 0) {
    const int4* p = (const int4*)cidx + n * 2;
    int4 u = p[0], v = p[1];
    r = make_ushort4((unsigned short)u.x, (unsigned short)u.z,
                     (unsigned short)v.x, (unsigned short)v.z);
  } else {
    int4 u = ((const int4*)cidx)[n];
    r = make_ushort4((unsigned short)u.x, (unsigned short)u.y,
                     (unsigned short)u.z, (unsigned short)u.w);
  }
  const unsigned w0 = (unsigned)r.x | ((unsigned)r.y << 16);
  const unsigned w1 = (unsigned)r.z | ((unsigned)r.w << 16);
  const bool dual  = ((l & 1) == 0);          // prod layer: dual-copy A
  const int  kmask = dual ? 15 : 31;

  unsigned hcnt = 0;                  // this lane's bank: 4 packed slot counts
  ushort4 mine = r;
  for (int k = 0; k < 64; ++k) {
    const unsigned a0 = __shfl(w0, k);
    const unsigned a1 = __shfl(w1, k);
    unsigned short v4[4] = {(unsigned short)(a0 & 0xffffu), (unsigned short)(a0 >> 16),
                            (unsigned short)(a1 & 0xffffu), (unsigned short)(a1 >> 16)};
    int b0[4], b1[4];
    unsigned c0[4], c1[4];
#pragma unroll
    for (int j = 0; j < 4; ++j) {
      b0[j] = v4[j] & kmask;
      b1[j] = dual ? (b0[j] ^ 8) : b0[j];
    }
#pragma unroll
    for (int j = 0; j < 4; ++j) c0[j] = __shfl(hcnt, b0[j]);
#pragma unroll
    for (int j = 0; j < 4; ++j) c1[j] = dual ? __shfl(hcnt, b1[j]) : 0u;

    int slot[4], keyj[4];
    unsigned short o[4];
    unsigned usedmask = 0;
#pragma unroll
    for (int j = 0; j < 4; ++j) {
      unsigned adj0 = 0, adj1 = 0;
#pragma unroll
      for (int p2 = 0; p2 < 4; ++p2)
        if (p2 < j) {
          if (keyj[p2] == b0[j]) adj0 += 1u << (8 * slot[p2]);
          if (dual && keyj[p2] == b1[j]) adj1 += 1u << (8 * slot[p2]);
        }
      const unsigned e0 = c0[j] + adj0;
      const unsigned e1 = dual ? (c1[j] + adj1) : 0xffffffffu;
      int best = 0, bm = 0; unsigned bv = 0x10000u;
#pragma unroll
      for (int s = 0; s < 4; ++s) {
        if ((usedmask >> s) & 1) continue;
        const unsigned q0 = (e0 >> (8 * s)) & 0xffu;
        if (q0 < bv) { bv = q0; best = s; bm = 0; }
        if (dual) {
          const unsigned q1 = (e1 >> (8 * s)) & 0xffu;
          if (q1 < bv) { bv = q1; best = s; bm = 1; }
        }
      }
      slot[j] = best; usedmask |= 1u << best;
      keyj[j] = bm ? b1[j] : b0[j];
      o[best] = dual ? (unsigned short)(((unsigned)bm << 12) |
                                        ((unsigned)v4[j] ^ ((unsigned)bm << 3)))
                     : v4[j];
    }
#pragma unroll
    for (int j = 0; j < 4; ++j)           // owning lane updates its bank
      if (lane == keyj[j]) hcnt += 1u << (8 * slot[j]);
    if (lane == k) mine = make_ushort4(o[0], o[1], o[2], o[3]);
  }
  out[n] = mine;   // coalesced ushort4 store
}

extern "C" void kernel_launch(void* const* d_in, const int* in_sizes, int n_in,
                              void* d_out, int out_size, void* d_ws, size_t ws_size,
                              hipStream_t stream) {
  const float* x          = (const float*)d_in[0];
  const unsigned char* mg = (const unsigned char*)d_in[1];
  const int* cidx         = (const int*)d_in[2];
  float* out              = (float*)d_out;

  (void)hipFuncSetAttribute((const void*)spn_packed,
                            hipFuncAttributeMaxDynamicSharedMemorySize, (int)SMEM);
  (void)hipFuncSetAttribute((const void*)spn_raw,
                            hipFuncAttributeMaxDynamicSharedMemorySize, (int)SMEM);

  const size_t need = (size_t)N_LAYERS * NODES * sizeof(ushort4);  // 256 KB
  if (ws_size >= need) {
    ushort4* packed = (ushort4*)d_ws;
    hipLaunchKernelGGL(prep_idx, dim3(N_LAYERS * 64), dim3(64), 0, stream,
                       cidx, packed);
    hipLaunchKernelGGL(spn_packed, dim3(BATCH / RPB), dim3(THREADS), SMEM, stream,
                       x, mg, packed, out);
  } else {
    hipLaunchKernelGGL(spn_raw, dim3(BATCH / RPB), dim3(THREADS), SMEM, stream,
                       x, mg, cidx, out);
  }
}

// Round 8
// 209.062 us; speedup vs baseline: 1.3157x; 1.3157x over previous
//
#include <hip/hip_runtime.h>

constexpr int N_VARS   = 2048;
constexpr int NODES    = 4096;
constexpr int N_LAYERS = 8;
constexpr int BATCH    = 8192;
constexpr int THREADS  = 256;               // 4 waves/block, 3 blocks/CU (48 KB LDS)
constexpr int RPB      = 2;                 // batch rows per block
constexpr int NPT      = NODES / THREADS;   // 16 nodes/thread/layer

// ---- bf16x2 word = row0 bf16 (low 16) | row1 bf16 (high 16) ----
__device__ __forceinline__ float bflo(unsigned w) { return __uint_as_float(w << 16); }
__device__ __forceinline__ float bfhi(unsigned w) { return __uint_as_float(w & 0xffff0000u); }
__device__ __forceinline__ unsigned bfpack(float a, float b) {   // RNE both
  unsigned ua = __float_as_uint(a), ub = __float_as_uint(b);
  ua = (ua + 0x7fffu + ((ua >> 16) & 1u)) >> 16;
  ub = (ub + 0x7fffu + ((ub >> 16) & 1u)) & 0xffff0000u;
  return ua | ub;
}

// MODE: 0 = pre-packed/balanced ushort4 (d_ws), 1 = raw int32, 2 = raw int64
template <int MODE>
__device__ __forceinline__ ushort4 get_idx(const void* p, int n) {
  if (MODE == 0) return ((const ushort4*)p)[n];
  if (MODE == 1) {
    int4 c = ((const int4*)p)[n];
    return make_ushort4((unsigned short)c.x, (unsigned short)c.y,
                        (unsigned short)c.z, (unsigned short)c.w);
  }
  const int* q = (const int*)p + (size_t)n * 8;
  return make_ushort4((unsigned short)q[0], (unsigned short)q[2],
                      (unsigned short)q[4], (unsigned short)q[6]);
}
template <int MODE> __device__ __forceinline__ size_t layer_bytes() {
  return MODE == 0 ? (size_t)NODES * 8 : MODE == 1 ? (size_t)NODES * 16
                                                   : (size_t)NODES * 32;
}

// Prod layer: register-stage all 16 idx loads (decouple L2 latency from the
// DS chain), then gather fp32 float2 from A, multiply, store bf16x2 to B.
template <int MODE>
__device__ __forceinline__ void prod_pass(const float2* A, unsigned* B,
                                          const void* idx, int t) {
  ushort4 ci[NPT];
#pragma unroll
  for (int i = 0; i < NPT; ++i) ci[i] = get_idx<MODE>(idx, t + i * THREADS);
#pragma unroll
  for (int i = 0; i < NPT; ++i) {
    const int n = t + i * THREADS;
    float2 a = A[ci[i].x], b = A[ci[i].y], d = A[ci[i].z], e = A[ci[i].w];
    B[n] = bfpack(a.x * b.x * d.x * e.x, a.y * b.y * d.y * e.y);
  }
}

// Sum layer: gather bf16x2 from B, add fp32, store fp32 float2 to A.
template <int MODE>
__device__ __forceinline__ void sum_pass(const unsigned* B, float2* A,
                                         const void* idx, int t) {
  ushort4 ci[NPT];
#pragma unroll
  for (int i = 0; i < NPT; ++i) ci[i] = get_idx<MODE>(idx, t + i * THREADS);
#pragma unroll
  for (int i = 0; i < NPT; ++i) {
    const int n = t + i * THREADS;
    unsigned a = B[ci[i].x], b = B[ci[i].y], d = B[ci[i].z], e = B[ci[i].w];
    A[n] = make_float2(bflo(a) + bflo(b) + bflo(d) + bflo(e),
                       bfhi(a) + bfhi(b) + bfhi(d) + bfhi(e));
  }
}

template <int MODE>
__device__ __forceinline__ void spn_body(const float* __restrict__ x,
                                         const unsigned char* __restrict__ marg,
                                         const void* __restrict__ idx,
                                         float* __restrict__ out,
                                         float2* A,          // 4096 fp32x2 = 32 KB
                                         unsigned* B) {      // 4096 bf16x2 = 16 KB
  const int t = threadIdx.x;
  const int row0 = blockIdx.x * RPB;
  const float* x0 = x + (size_t)row0 * N_VARS;
  const float* x1 = x0 + N_VARS;

#pragma unroll
  for (int i = 0; i < N_VARS / THREADS; ++i) {  // 8 iterations
    const int j = t + i * THREADS;
    const float a = x0[j], b = x1[j];
    const bool m = marg[j] != 0;
    A[j]          = make_float2(m ? 1.f : a,       m ? 1.f : b);
    A[N_VARS + j] = make_float2(m ? 1.f : 1.f - a, m ? 1.f : 1.f - b);
  }

  const char* ib = (const char*)idx;
  const size_t LB = layer_bytes<MODE>();
  __syncthreads();
  prod_pass<MODE>(A, B, ib + 0 * LB, t); __syncthreads();   // L0
  sum_pass <MODE>(B, A, ib + 1 * LB, t); __syncthreads();   // L1
  prod_pass<MODE>(A, B, ib + 2 * LB, t); __syncthreads();   // L2
  sum_pass <MODE>(B, A, ib + 3 * LB, t); __syncthreads();   // L3
  prod_pass<MODE>(A, B, ib + 4 * LB, t); __syncthreads();   // L4
  sum_pass <MODE>(B, A, ib + 5 * LB, t); __syncthreads();   // L5
  prod_pass<MODE>(A, B, ib + 6 * LB, t); __syncthreads();   // L6

  // L7 (sum) fused into node reduction.
  float s0 = 0.f, s1 = 0.f;
  {
    const void* L7 = ib + 7 * LB;
    ushort4 ci[NPT];
#pragma unroll
    for (int i = 0; i < NPT; ++i) ci[i] = get_idx<MODE>(L7, t + i * THREADS);
#pragma unroll
    for (int i = 0; i < NPT; ++i) {
      unsigned a = B[ci[i].x], b = B[ci[i].y], d = B[ci[i].z], e = B[ci[i].w];
      s0 += bflo(a) + bflo(b) + bflo(d) + bflo(e);
      s1 += bfhi(a) + bfhi(b) + bfhi(d) + bfhi(e);
    }
  }
#pragma unroll
  for (int off = 32; off > 0; off >>= 1) {
    s0 += __shfl_down(s0, off);
    s1 += __shfl_down(s1, off);
  }
  if ((t & 63) == 0) A[t >> 6] = make_float2(s0, s1);  // 4 wave partials
  __syncthreads();
  if (t == 0) {
    float2 tot = A[0];
#pragma unroll
    for (int w = 1; w < THREADS / 64; ++w) { tot.x += A[w].x; tot.y += A[w].y; }
    ((float2*)out)[blockIdx.x] = tot;
  }
}

__global__ __launch_bounds__(THREADS, 3) void spn_packed(
    const float* __restrict__ x, const unsigned char* __restrict__ marg,
    const ushort4* __restrict__ idx, float* __restrict__ out) {
  __shared__ float2   A[NODES];   // 32 KB
  __shared__ unsigned B[NODES];   // 16 KB -> 48 KB, 3 blocks/CU
  spn_body<0>(x, marg, idx, out, A, B);
}

__global__ __launch_bounds__(THREADS, 3) void spn_raw(
    const float* __restrict__ x, const unsigned char* __restrict__ marg,
    const int* __restrict__ cidx, float* __restrict__ out) {
  __shared__ float2   A[NODES];
  __shared__ unsigned B[NODES];
  int acc = 0;  // int64 storage => odd words all zero (indices < 4096)
#pragma unroll
  for (int k = 0; k < 8; ++k) acc |= cidx[2 * k + 1];
  if (acc == 0) spn_body<2>(x, marg, cidx, out, A, B);
  else          spn_body<1>(x, marg, cidx, out, A, B);
}

// Fused pack + bank-balance, one WAVE per 64-node instruction-group.
// Prod/sum commute -> permute each node's 4 children across the 4 gather
// slots so each slot's per-bank multiplicity stays near hist/4.
//   even layers read A (float2, 8 B granule)  -> bank-pair = c & 15
//   odd  layers read B (bf16x2, 4 B granule)  -> bank      = c & 31
// Histogram distributed in registers: lane b holds bank b's four 8-bit slot
// counts packed in one u32; all lanes compute every decision redundantly
// from __shfl'd data (pure function -> identical results).
__global__ __launch_bounds__(64) void prep_idx(const int* __restrict__ cidx,
                                               ushort4* __restrict__ out) {
  const int gid  = blockIdx.x;        // 0..511
  const int l    = gid >> 6;          // layer
  const int cgrp = gid & 63;          // 64-node chunk within layer
  const int lane = threadIdx.x;       // 0..63
  const size_t n = (size_t)l * NODES + cgrp * 64 + lane;

  int acc = 0;                        // i64 storage detect (uniform)
#pragma unroll
  for (int k = 0; k < 8; ++k) acc |= cidx[2 * k + 1];

  ushort4 r;
  if (acc == 0) {
    const int4* p = (const int4*)cidx + n * 2;
    int4 u = p[0], v = p[1];
    r = make_ushort4((unsigned short)u.x, (unsigned short)u.z,
                     (unsigned short)v.x, (unsigned short)v.z);
  } else {
    int4 u = ((const int4*)cidx)[n];
    r = make_ushort4((unsigned short)u.x, (unsigned short)u.y,
                     (unsigned short)u.z, (unsigned short)u.w);
  }
  const unsigned w0 = (unsigned)r.x | ((unsigned)r.y << 16);
  const unsigned w1 = (unsigned)r.z | ((unsigned)r.w << 16);
  const int mask = ((l & 1) == 0) ? 15 : 31;

  unsigned hcnt = 0;                  // this lane's bank: 4 packed slot counts
  ushort4 mine = r;
  for (int k = 0; k < 64; ++k) {
    const unsigned a0 = __shfl(w0, k);
    const unsigned a1 = __shfl(w1, k);
    unsigned short v4[4] = {(unsigned short)(a0 & 0xffffu), (unsigned short)(a0 >> 16),
                            (unsigned short)(a1 & 0xffffu), (unsigned short)(a1 >> 16)};
    int bank[4];
#pragma unroll
    for (int j = 0; j < 4; ++j) bank[j] = v4[j] & mask;
    unsigned cnt[4];
#pragma unroll
    for (int j = 0; j < 4; ++j) cnt[j] = __shfl(hcnt, bank[j]);
    int slot[4]; unsigned used = 0;
    unsigned short o[4];
#pragma unroll
    for (int j = 0; j < 4; ++j) {
      unsigned eff = cnt[j];
#pragma unroll
      for (int p2 = 0; p2 < 4; ++p2)      // account earlier dup-bank children
        if (p2 < j && bank[p2] == bank[j]) eff += 1u << (8 * slot[p2]);
      const unsigned m2 = eff | used;     // used slots -> 0xff, never min
      int best = 0; unsigned bv = m2 & 0xffu;
#pragma unroll
      for (int s = 1; s < 4; ++s) {
        const unsigned q = (m2 >> (8 * s)) & 0xffu;
        if (q < bv) { bv = q; best = s; }
      }
      slot[j] = best; used |= 0xffu << (8 * best); o[best] = v4[j];
    }
#pragma unroll
    for (int j = 0; j < 4; ++j)           // owning lane updates its bank
      if (lane == bank[j]) hcnt += 1u << (8 * slot[j]);
    if (lane == k) mine = make_ushort4(o[0], o[1], o[2], o[3]);
  }
  out[n] = mine;   // coalesced ushort4 store
}

extern "C" void kernel_launch(void* const* d_in, const int* in_sizes, int n_in,
                              void* d_out, int out_size, void* d_ws, size_t ws_size,
                              hipStream_t stream) {
  const float* x          = (const float*)d_in[0];
  const unsigned char* mg = (const unsigned char*)d_in[1];
  const int* cidx         = (const int*)d_in[2];
  float* out              = (float*)d_out;

  const size_t need = (size_t)N_LAYERS * NODES * sizeof(ushort4);  // 256 KB
  if (ws_size >= need) {
    ushort4* packed = (ushort4*)d_ws;
    hipLaunchKernelGGL(prep_idx, dim3(N_LAYERS * 64), dim3(64), 0, stream,
                       cidx, packed);
    hipLaunchKernelGGL(spn_packed, dim3(BATCH / RPB), dim3(THREADS), 0, stream,
                       x, mg, packed, out);
  } else {
    hipLaunchKernelGGL(spn_raw, dim3(BATCH / RPB), dim3(THREADS), 0, stream,
                       x, mg, cidx, out);
  }
}